// Round 5
// baseline (68.054 us; speedup 1.0000x reference)
//
#include <hip/hip_runtime.h>
#include <math.h>

#define B_ 4
#define Q_ 1024
#define K_ 1024
#define DIN_ 256
#define H_ 64
#define DV_ 128
#define KT 64
#define MASKV -1000000.0f
#define C2LOG2E 2.8853900817779268f   // 2*log2(e): exp(2x)=exp2(C*x)
#define LOG2E 1.4426950408889634f

__device__ __forceinline__ float fexp2(float x) {
#if __has_builtin(__builtin_amdgcn_exp2f)
  return __builtin_amdgcn_exp2f(x);
#else
  return exp2f(x);
#endif
}
__device__ __forceinline__ float frcp(float x) {
#if __has_builtin(__builtin_amdgcn_rcpf)
  return __builtin_amdgcn_rcpf(x);
#else
  return 1.0f / x;
#endif
}
__device__ __forceinline__ float bitsf(unsigned u) { return __uint_as_float(u); }
__device__ __forceinline__ unsigned short f2bf(float f) {  // RNE float->bf16
  unsigned u = __float_as_uint(f);
  return (unsigned short)((u + 0x7FFFu + ((u >> 16) & 1u)) >> 16);
}

// blocks [0,512): row projections EQ/EK = exp2(C * row.W), 16 rows/block
// blocks [512,1024): values -> bf16 (packed, RNE).
__global__ __launch_bounds__(256, 4) void prep_kernel(
    const float* __restrict__ queries, const float* __restrict__ keys,
    const float* __restrict__ values,
    const float* __restrict__ Wq, const float* __restrict__ Wk,
    float* __restrict__ eq, float* __restrict__ ek,
    unsigned short* __restrict__ vb) {
  int bid = blockIdx.x;
  int t = threadIdx.x;
  if (bid >= 512) {
    int i = ((bid - 512) * 256 + t) * 4;     // 512*256*4 = 524288 = B*K*DV
    float4 v = *(const float4*)&values[i];
    ushort4 o;
    o.x = f2bf(v.x); o.y = f2bf(v.y); o.z = f2bf(v.z); o.w = f2bf(v.w);
    *(ushort4*)&vb[i] = o;
    return;
  }
  int w = t >> 6, lane = t & 63;
  int r0 = __builtin_amdgcn_readfirstlane(bid * 16 + w * 4);  // rows r0..r0+3
  const float* src;
  const float* W;
  float* dst;
  if (r0 < B_ * Q_) {
    src = queries + r0 * DIN_; W = Wq; dst = eq + r0 * H_;
  } else {
    int kr = r0 - B_ * Q_;
    src = keys + kr * DIN_; W = Wk; dst = ek + kr * H_;
  }
  float a00 = 0.f, a01 = 0.f, a10 = 0.f, a11 = 0.f;
  float a20 = 0.f, a21 = 0.f, a30 = 0.f, a31 = 0.f;
#pragma unroll 8
  for (int d = 0; d < DIN_; d += 2) {
    float w0 = W[d * H_ + lane];
    float w1 = W[(d + 1) * H_ + lane];
    a00 = fmaf(w0, src[d], a00);             a01 = fmaf(w1, src[d + 1], a01);
    a10 = fmaf(w0, src[DIN_ + d], a10);      a11 = fmaf(w1, src[DIN_ + d + 1], a11);
    a20 = fmaf(w0, src[2 * DIN_ + d], a20);  a21 = fmaf(w1, src[2 * DIN_ + d + 1], a21);
    a30 = fmaf(w0, src[3 * DIN_ + d], a30);  a31 = fmaf(w1, src[3 * DIN_ + d + 1], a31);
  }
  dst[lane]          = fexp2((a00 + a01) * C2LOG2E);
  dst[H_ + lane]     = fexp2((a10 + a11) * C2LOG2E);
  dst[2 * H_ + lane] = fexp2((a20 + a21) * C2LOG2E);
  dst[3 * H_ + lane] = fexp2((a30 + a31) * C2LOG2E);
}

// Flash attention over ONE K-split span (span = K_/ns keys, usually 1 tile).
// Wave owns 2 queries; lane owns 1 key slot. ek row forced register-resident
// via sched_barrier. Writes unnormalized partials (m, l, o).
__global__ __launch_bounds__(256, 4) void attn_kernel(
    const float* __restrict__ eq, const float* __restrict__ ek,
    const unsigned* __restrict__ vb32, const float* __restrict__ wv,
    const int* __restrict__ vlen,
    float* __restrict__ pml, float* __restrict__ po,
    int ns, int span) {
  __shared__ __align__(16) float p_s[4][2][KT];
  int t = threadIdx.x;
  int lane = t & 63;
  int w = t >> 6;
  int bid = blockIdx.x;
  int s = blockIdx.y;
  int b = bid >> 7;                           // 128 blocks per batch
  int q0 = __builtin_amdgcn_readfirstlane(((bid & 127) * 4 + w) * 2);
  int kv = vlen[b];
  int g = b * Q_ + q0;                        // global query row (and g+1)
  int k_lo = s * span;

  if (k_lo >= kv) {                           // inactive split: ml only
    if (lane == 0) {
      *(float2*)&pml[(g * ns + s) * 2] = make_float2(-1e38f, 0.f);
      *(float2*)&pml[((g + 1) * ns + s) * 2] = make_float2(-1e38f, 0.f);
    }
    return;
  }

  const float* eqa = eq + (long)g * H_;
  const float* eqb = eqa + H_;
  const float* ekb = ek + b * K_ * H_;
  const unsigned* vbb = vb32 + b * K_ * (DV_ / 2) + lane;  // + row*64

  // wsum = sum of w_v via wave shuffle reduce (lane-parallel)
  float wsum = wv[lane];
#pragma unroll
  for (int sh = 32; sh >= 1; sh >>= 1) wsum += __shfl_xor(wsum, sh);

  float ma = -1e38f, mb = -1e38f, la = 0.f, lb = 0.f;
  float oa0 = 0.f, oa1 = 0.f, ob0 = 0.f, ob1 = 0.f;
  int tile0 = k_lo >> 6;
  int tileE = min((kv + KT - 1) >> 6, (k_lo + span) >> 6);

  for (int tile = tile0; tile < tileE; ++tile) {
    int k0 = tile * KT;
    // ek row for this lane's key -> registers, ALL issued before score phase
    const float4* ekr4 = (const float4*)(ekb + (k0 + lane) * H_);
    float ekf[64];
#pragma unroll
    for (int j = 0; j < 16; ++j) {
      float4 tv = ekr4[j];
      ekf[j * 4] = tv.x; ekf[j * 4 + 1] = tv.y;
      ekf[j * 4 + 2] = tv.z; ekf[j * 4 + 3] = tv.w;
    }
    __builtin_amdgcn_sched_barrier(0);  // keep loads above, score below

    // scores: x = wsum - 2 * sum_h wv[h] / (1 + EQ[h]*EK[h])  (pure compute)
    float aa0 = 0.f, aa1 = 0.f, ab0 = 0.f, ab1 = 0.f;
#pragma unroll
    for (int h = 0; h < H_; ++h) {
      float ekv = ekf[h];
      float wvh = wv[h];
      float ra = frcp(fmaf(ekv, eqa[h], 1.0f));
      float rb = frcp(fmaf(ekv, eqb[h], 1.0f));
      if (h & 1) { aa1 = fmaf(wvh, ra, aa1); ab1 = fmaf(wvh, rb, ab1); }
      else       { aa0 = fmaf(wvh, ra, aa0); ab0 = fmaf(wvh, rb, ab0); }
    }
    float xa = fmaf(-2.f, aa0 + aa1, wsum);
    float xb = fmaf(-2.f, ab0 + ab1, wsum);
    if (k0 + lane >= kv) { xa = MASKV; xb = MASKV; }

    // wave-local online softmax for both queries (interleaved reduces)
    float mta = xa, mtb = xb;
#pragma unroll
    for (int sh = 32; sh >= 1; sh >>= 1) {
      mta = fmaxf(mta, __shfl_xor(mta, sh));
      mtb = fmaxf(mtb, __shfl_xor(mtb, sh));
    }
    float mna = fmaxf(ma, mta), mnb = fmaxf(mb, mtb);
    float pa = fexp2((xa - mna) * LOG2E);
    float pb = fexp2((xb - mnb) * LOG2E);
    float psa = pa, psb = pb;
#pragma unroll
    for (int sh = 32; sh >= 1; sh >>= 1) {
      psa += __shfl_xor(psa, sh);
      psb += __shfl_xor(psb, sh);
    }
    float sca = fexp2((ma - mna) * LOG2E);
    float scb = fexp2((mb - mnb) * LOG2E);
    la = fmaf(la, sca, psa); lb = fmaf(lb, scb, psb);
    ma = mna; mb = mnb;
    oa0 *= sca; oa1 *= sca; ob0 *= scb; ob1 *= scb;
    p_s[w][0][lane] = pa;
    p_s[w][1][lane] = pb;   // same-wave write->read; compiler inserts lgkmcnt

    // PV: p broadcast from wave-private LDS, V as packed bf16 pairs
#pragma unroll 4
    for (int k4 = 0; k4 < KT / 4; ++k4) {
      float4 pa4 = *(const float4*)&p_s[w][0][k4 * 4];
      float4 pb4 = *(const float4*)&p_s[w][1][k4 * 4];
      int r = (k0 + k4 * 4) * (DV_ / 2);
      unsigned vv0 = vbb[r];
      unsigned vv1 = vbb[r + 64];
      unsigned vv2 = vbb[r + 128];
      unsigned vv3 = vbb[r + 192];
      float v00 = bitsf(vv0 << 16), v01 = bitsf(vv0 & 0xFFFF0000u);
      float v10 = bitsf(vv1 << 16), v11 = bitsf(vv1 & 0xFFFF0000u);
      float v20 = bitsf(vv2 << 16), v21 = bitsf(vv2 & 0xFFFF0000u);
      float v30 = bitsf(vv3 << 16), v31 = bitsf(vv3 & 0xFFFF0000u);
      oa0 = fmaf(pa4.x, v00, oa0); oa1 = fmaf(pa4.x, v01, oa1);
      ob0 = fmaf(pb4.x, v00, ob0); ob1 = fmaf(pb4.x, v01, ob1);
      oa0 = fmaf(pa4.y, v10, oa0); oa1 = fmaf(pa4.y, v11, oa1);
      ob0 = fmaf(pb4.y, v10, ob0); ob1 = fmaf(pb4.y, v11, ob1);
      oa0 = fmaf(pa4.z, v20, oa0); oa1 = fmaf(pa4.z, v21, oa1);
      ob0 = fmaf(pb4.z, v20, ob0); ob1 = fmaf(pb4.z, v21, ob1);
      oa0 = fmaf(pa4.w, v30, oa0); oa1 = fmaf(pa4.w, v31, oa1);
      ob0 = fmaf(pb4.w, v30, ob0); ob1 = fmaf(pb4.w, v31, ob1);
    }
  }

  // unnormalized partials
  long pbase = ((long)g * ns + s) * DV_ + lane * 2;
  *(float2*)&po[pbase] = make_float2(oa0, oa1);
  *(float2*)&po[pbase + (long)ns * DV_] = make_float2(ob0, ob1);
  if (lane == 0) {
    *(float2*)&pml[(g * ns + s) * 2] = make_float2(ma, la);
    *(float2*)&pml[((g + 1) * ns + s) * 2] = make_float2(mb, lb);
  }
}

// Merge ns partials per query row: O = sum_s o_s*e^{m_s-M}, L likewise.
__global__ __launch_bounds__(256, 4) void combine_kernel(
    const float* __restrict__ pml, const float* __restrict__ po,
    float* __restrict__ out, int ns) {
  int t = threadIdx.x;
  int lane = t & 63;
  int w = t >> 6;
  int qrow = blockIdx.x * 4 + w;
  float M = -1e38f;
  for (int s = 0; s < ns; ++s) {
    float2 v = *(const float2*)&pml[(qrow * ns + s) * 2];
    M = fmaxf(M, v.x);
  }
  float L = 0.f, ax = 0.f, ay = 0.f;
  for (int s = 0; s < ns; ++s) {
    float2 v = *(const float2*)&pml[(qrow * ns + s) * 2];
    if (v.y > 0.f) {                  // wave-uniform branch
      float wgt = fexp2((v.x - M) * LOG2E);
      L = fmaf(v.y, wgt, L);
      float2 o2 = *(const float2*)&po[((long)qrow * ns + s) * DV_ + lane * 2];
      ax = fmaf(o2.x, wgt, ax);
      ay = fmaf(o2.y, wgt, ay);
    }
  }
  float inv = frcp(L);
  *(float2*)&out[(long)qrow * DV_ + lane * 2] = make_float2(ax * inv, ay * inv);
}

extern "C" void kernel_launch(void* const* d_in, const int* in_sizes, int n_in,
                              void* d_out, int out_size, void* d_ws, size_t ws_size,
                              hipStream_t stream) {
  const float* queries = (const float*)d_in[0];
  const float* keys    = (const float*)d_in[1];
  const float* values  = (const float*)d_in[2];
  const int*   vl      = (const int*)d_in[3];
  const float* Wq      = (const float*)d_in[4];
  const float* Wk      = (const float*)d_in[5];
  const float* wv      = (const float*)d_in[6];
  float* out = (float*)d_out;

  // fixed buffers: eq 1MB, ek 1MB, vb 1MB
  float* eq = (float*)d_ws;
  float* ek = eq + (size_t)B_ * Q_ * H_;
  unsigned short* vb = (unsigned short*)(ek + (size_t)B_ * K_ * H_);
  char* dyn = (char*)(vb + (size_t)B_ * K_ * DV_);
  size_t fixed = (size_t)(dyn - (char*)d_ws);

  // choose K-split count by available workspace (deterministic per session)
  int ns = 2;
  for (int cand = 16; cand >= 2; cand >>= 1) {
    size_t need = fixed + (size_t)B_ * Q_ * cand * 8          // pml
                + (size_t)B_ * Q_ * cand * DV_ * 4;           // po
    if (ws_size >= need) { ns = cand; break; }
  }
  int span = K_ / ns;
  float* pml = (float*)dyn;
  float* po = pml + (size_t)B_ * Q_ * ns * 2;

  prep_kernel<<<dim3(1024), dim3(256), 0, stream>>>(
      queries, keys, values, Wq, Wk, eq, ek, vb);
  attn_kernel<<<dim3(B_ * (Q_ / 8), ns), dim3(256), 0, stream>>>(
      eq, ek, (const unsigned*)vb, wv, vl, pml, po, ns, span);
  combine_kernel<<<dim3(B_ * Q_ / 4), dim3(256), 0, stream>>>(pml, po, out, ns);
}

// Round 6
// 59.629 us; speedup vs baseline: 1.1413x; 1.1413x over previous
//
#include <hip/hip_runtime.h>
#include <math.h>

#define B_ 4
#define Q_ 1024
#define K_ 1024
#define DIN_ 256
#define H_ 64
#define DV_ 128
#define KT 64
#define MASKV -1000000.0f
#define C2LOG2E 2.8853900817779268f   // 2*log2(e): exp(2x)=exp2(C*x)
#define LOG2E 1.4426950408889634f

__device__ __forceinline__ float fexp2(float x) {
#if __has_builtin(__builtin_amdgcn_exp2f)
  return __builtin_amdgcn_exp2f(x);
#else
  return exp2f(x);
#endif
}
__device__ __forceinline__ float frcp(float x) {
#if __has_builtin(__builtin_amdgcn_rcpf)
  return __builtin_amdgcn_rcpf(x);
#else
  return 1.0f / x;
#endif
}
__device__ __forceinline__ float bitsf(unsigned u) { return __uint_as_float(u); }
__device__ __forceinline__ unsigned short f2bf(float f) {  // RNE float->bf16
  unsigned u = __float_as_uint(f);
  return (unsigned short)((u + 0x7FFFu + ((u >> 16) & 1u)) >> 16);
}

// blocks [0,512): row projections EQ/EK = exp2(C * row.W), 16 rows/block
// blocks [512,1024): values -> bf16 (packed, RNE).
__global__ __launch_bounds__(256, 4) void prep_kernel(
    const float* __restrict__ queries, const float* __restrict__ keys,
    const float* __restrict__ values,
    const float* __restrict__ Wq, const float* __restrict__ Wk,
    float* __restrict__ eq, float* __restrict__ ek,
    unsigned short* __restrict__ vb) {
  int bid = blockIdx.x;
  int t = threadIdx.x;
  if (bid >= 512) {
    int i = ((bid - 512) * 256 + t) * 4;     // 512*256*4 = 524288 = B*K*DV
    float4 v = *(const float4*)&values[i];
    ushort4 o;
    o.x = f2bf(v.x); o.y = f2bf(v.y); o.z = f2bf(v.z); o.w = f2bf(v.w);
    *(ushort4*)&vb[i] = o;
    return;
  }
  int w = t >> 6, lane = t & 63;
  int r0 = __builtin_amdgcn_readfirstlane(bid * 16 + w * 4);  // rows r0..r0+3
  const float* src;
  const float* W;
  float* dst;
  if (r0 < B_ * Q_) {
    src = queries + r0 * DIN_; W = Wq; dst = eq + r0 * H_;
  } else {
    int kr = r0 - B_ * Q_;
    src = keys + kr * DIN_; W = Wk; dst = ek + kr * H_;
  }
  float a00 = 0.f, a01 = 0.f, a10 = 0.f, a11 = 0.f;
  float a20 = 0.f, a21 = 0.f, a30 = 0.f, a31 = 0.f;
#pragma unroll 8
  for (int d = 0; d < DIN_; d += 2) {
    float w0 = W[d * H_ + lane];
    float w1 = W[(d + 1) * H_ + lane];
    a00 = fmaf(w0, src[d], a00);             a01 = fmaf(w1, src[d + 1], a01);
    a10 = fmaf(w0, src[DIN_ + d], a10);      a11 = fmaf(w1, src[DIN_ + d + 1], a11);
    a20 = fmaf(w0, src[2 * DIN_ + d], a20);  a21 = fmaf(w1, src[2 * DIN_ + d + 1], a21);
    a30 = fmaf(w0, src[3 * DIN_ + d], a30);  a31 = fmaf(w1, src[3 * DIN_ + d + 1], a31);
  }
  dst[lane]          = fexp2((a00 + a01) * C2LOG2E);
  dst[H_ + lane]     = fexp2((a10 + a11) * C2LOG2E);
  dst[2 * H_ + lane] = fexp2((a20 + a21) * C2LOG2E);
  dst[3 * H_ + lane] = fexp2((a30 + a31) * C2LOG2E);
}

// Flash attention over ONE K-split span (span = K_/ns keys = 1 tile at ns=16).
// ek tile staged ONCE per block into LDS with coalesced loads (shared by all
// 4 waves); lane reads its key row via ds_read_b128, conflict-penalty-free
// with pad 4 (banks (4k+h)%32, uniform). Wave owns 2 queries; lane 1 key.
__global__ __launch_bounds__(256, 8) void attn_kernel(
    const float* __restrict__ eq, const float* __restrict__ ek,
    const unsigned* __restrict__ vb32, const float* __restrict__ wv,
    const int* __restrict__ vlen,
    float* __restrict__ pml, float* __restrict__ po,
    int ns, int span) {
  __shared__ __align__(16) float ek_s[KT][H_ + 4];   // pad 4: 16B-aligned rows
  __shared__ __align__(16) float p_s[4][2][KT];
  int t = threadIdx.x;
  int lane = t & 63;
  int w = t >> 6;
  int bid = blockIdx.x;
  int s = blockIdx.y;
  int b = bid >> 7;                           // 128 blocks per batch
  int q0 = __builtin_amdgcn_readfirstlane(((bid & 127) * 4 + w) * 2);
  int kv = vlen[b];
  int g = b * Q_ + q0;                        // global query row (and g+1)
  int k_lo = s * span;

  if (k_lo >= kv) {                           // inactive split: ml only
    if (lane == 0) {
      *(float2*)&pml[(g * ns + s) * 2] = make_float2(-1e38f, 0.f);
      *(float2*)&pml[((g + 1) * ns + s) * 2] = make_float2(-1e38f, 0.f);
    }
    return;
  }

  const float* eqa = eq + (long)g * H_;
  const float* eqb = eqa + H_;
  const float* ekb = ek + b * K_ * H_;
  const unsigned* vbb = vb32 + b * K_ * (DV_ / 2) + lane;  // + row*64

  // wsum = sum of w_v via wave shuffle reduce (lane-parallel)
  float wsum = wv[lane];
#pragma unroll
  for (int sh = 32; sh >= 1; sh >>= 1) wsum += __shfl_xor(wsum, sh);

  float ma = -1e38f, mb = -1e38f, la = 0.f, lb = 0.f;
  float oa0 = 0.f, oa1 = 0.f, ob0 = 0.f, ob1 = 0.f;
  int tile0 = k_lo >> 6;
  int tileE = min((kv + KT - 1) >> 6, (k_lo + span) >> 6);

  for (int tile = tile0; tile < tileE; ++tile) {
    int k0 = tile * KT;

    // ---- stage ek tile [64 keys][64 h] into LDS, coalesced ----
    __syncthreads();                           // prior tile's readers done
    {
      const float4* gsrc = (const float4*)(ekb + (size_t)k0 * H_);
#pragma unroll
      for (int i = 0; i < 4; ++i) {
        int f4 = i * 256 + t;
        int kk = f4 >> 4, h4 = f4 & 15;
        float4 v = gsrc[f4];
        *(float4*)&ek_s[kk][h4 * 4] = v;
      }
    }
    __syncthreads();

    // scores: x = wsum - 2 * sum_h wv[h] / (1 + EQ[h]*EK[h])
    const float* ekrow = ek_s[lane];
    float aa0 = 0.f, aa1 = 0.f, ab0 = 0.f, ab1 = 0.f;
#pragma unroll
    for (int h4 = 0; h4 < H_ / 4; ++h4) {
      float4 e4 = *(const float4*)&ekrow[h4 * 4];
#pragma unroll
      for (int j = 0; j < 4; ++j) {
        int h = h4 * 4 + j;
        float ekv = (j == 0) ? e4.x : (j == 1) ? e4.y : (j == 2) ? e4.z : e4.w;
        float wvh = wv[h];
        float ra = frcp(fmaf(ekv, eqa[h], 1.0f));
        float rb = frcp(fmaf(ekv, eqb[h], 1.0f));
        if (j & 1) { aa1 = fmaf(wvh, ra, aa1); ab1 = fmaf(wvh, rb, ab1); }
        else       { aa0 = fmaf(wvh, ra, aa0); ab0 = fmaf(wvh, rb, ab0); }
      }
    }
    float xa = fmaf(-2.f, aa0 + aa1, wsum);
    float xb = fmaf(-2.f, ab0 + ab1, wsum);
    if (k0 + lane >= kv) { xa = MASKV; xb = MASKV; }

    // wave-local online softmax for both queries (interleaved reduces)
    float mta = xa, mtb = xb;
#pragma unroll
    for (int sh = 32; sh >= 1; sh >>= 1) {
      mta = fmaxf(mta, __shfl_xor(mta, sh));
      mtb = fmaxf(mtb, __shfl_xor(mtb, sh));
    }
    float mna = fmaxf(ma, mta), mnb = fmaxf(mb, mtb);
    float pa = fexp2((xa - mna) * LOG2E);
    float pb = fexp2((xb - mnb) * LOG2E);
    float psa = pa, psb = pb;
#pragma unroll
    for (int sh = 32; sh >= 1; sh >>= 1) {
      psa += __shfl_xor(psa, sh);
      psb += __shfl_xor(psb, sh);
    }
    float sca = fexp2((ma - mna) * LOG2E);
    float scb = fexp2((mb - mnb) * LOG2E);
    la = fmaf(la, sca, psa); lb = fmaf(lb, scb, psb);
    ma = mna; mb = mnb;
    oa0 *= sca; oa1 *= sca; ob0 *= scb; ob1 *= scb;
    p_s[w][0][lane] = pa;
    p_s[w][1][lane] = pb;   // same-wave write->read; compiler inserts lgkmcnt

    // PV: p broadcast from wave-private LDS, V as packed bf16 pairs
#pragma unroll 4
    for (int k4 = 0; k4 < KT / 4; ++k4) {
      float4 pa4 = *(const float4*)&p_s[w][0][k4 * 4];
      float4 pb4 = *(const float4*)&p_s[w][1][k4 * 4];
      int r = (k0 + k4 * 4) * (DV_ / 2);
      unsigned vv0 = vbb[r];
      unsigned vv1 = vbb[r + 64];
      unsigned vv2 = vbb[r + 128];
      unsigned vv3 = vbb[r + 192];
      float v00 = bitsf(vv0 << 16), v01 = bitsf(vv0 & 0xFFFF0000u);
      float v10 = bitsf(vv1 << 16), v11 = bitsf(vv1 & 0xFFFF0000u);
      float v20 = bitsf(vv2 << 16), v21 = bitsf(vv2 & 0xFFFF0000u);
      float v30 = bitsf(vv3 << 16), v31 = bitsf(vv3 & 0xFFFF0000u);
      oa0 = fmaf(pa4.x, v00, oa0); oa1 = fmaf(pa4.x, v01, oa1);
      ob0 = fmaf(pb4.x, v00, ob0); ob1 = fmaf(pb4.x, v01, ob1);
      oa0 = fmaf(pa4.y, v10, oa0); oa1 = fmaf(pa4.y, v11, oa1);
      ob0 = fmaf(pb4.y, v10, ob0); ob1 = fmaf(pb4.y, v11, ob1);
      oa0 = fmaf(pa4.z, v20, oa0); oa1 = fmaf(pa4.z, v21, oa1);
      ob0 = fmaf(pb4.z, v20, ob0); ob1 = fmaf(pb4.z, v21, ob1);
      oa0 = fmaf(pa4.w, v30, oa0); oa1 = fmaf(pa4.w, v31, oa1);
      ob0 = fmaf(pb4.w, v30, ob0); ob1 = fmaf(pb4.w, v31, ob1);
    }
  }

  // unnormalized partials
  long pbase = ((long)g * ns + s) * DV_ + lane * 2;
  *(float2*)&po[pbase] = make_float2(oa0, oa1);
  *(float2*)&po[pbase + (long)ns * DV_] = make_float2(ob0, ob1);
  if (lane == 0) {
    *(float2*)&pml[(g * ns + s) * 2] = make_float2(ma, la);
    *(float2*)&pml[((g + 1) * ns + s) * 2] = make_float2(mb, lb);
  }
}

// Merge ns partials per query row: O = sum_s o_s*e^{m_s-M}, L likewise.
__global__ __launch_bounds__(256, 4) void combine_kernel(
    const float* __restrict__ pml, const float* __restrict__ po,
    float* __restrict__ out, int ns) {
  int t = threadIdx.x;
  int lane = t & 63;
  int w = t >> 6;
  int qrow = blockIdx.x * 4 + w;
  float M = -1e38f;
  for (int s = 0; s < ns; ++s) {
    float2 v = *(const float2*)&pml[(qrow * ns + s) * 2];
    M = fmaxf(M, v.x);
  }
  float L = 0.f, ax = 0.f, ay = 0.f;
  for (int s = 0; s < ns; ++s) {
    float2 v = *(const float2*)&pml[(qrow * ns + s) * 2];
    if (v.y > 0.f) {                  // wave-uniform branch
      float wgt = fexp2((v.x - M) * LOG2E);
      L = fmaf(v.y, wgt, L);
      float2 o2 = *(const float2*)&po[((long)qrow * ns + s) * DV_ + lane * 2];
      ax = fmaf(o2.x, wgt, ax);
      ay = fmaf(o2.y, wgt, ay);
    }
  }
  float inv = frcp(L);
  *(float2*)&out[(long)qrow * DV_ + lane * 2] = make_float2(ax * inv, ay * inv);
}

extern "C" void kernel_launch(void* const* d_in, const int* in_sizes, int n_in,
                              void* d_out, int out_size, void* d_ws, size_t ws_size,
                              hipStream_t stream) {
  const float* queries = (const float*)d_in[0];
  const float* keys    = (const float*)d_in[1];
  const float* values  = (const float*)d_in[2];
  const int*   vl      = (const int*)d_in[3];
  const float* Wq      = (const float*)d_in[4];
  const float* Wk      = (const float*)d_in[5];
  const float* wv      = (const float*)d_in[6];
  float* out = (float*)d_out;

  // fixed buffers: eq 1MB, ek 1MB, vb 1MB
  float* eq = (float*)d_ws;
  float* ek = eq + (size_t)B_ * Q_ * H_;
  unsigned short* vb = (unsigned short*)(ek + (size_t)B_ * K_ * H_);
  char* dyn = (char*)(vb + (size_t)B_ * K_ * DV_);
  size_t fixed = (size_t)(dyn - (char*)d_ws);

  // choose K-split count by available workspace (deterministic per session)
  int ns = 2;
  for (int cand = 16; cand >= 2; cand >>= 1) {
    size_t need = fixed + (size_t)B_ * Q_ * cand * 8          // pml
                + (size_t)B_ * Q_ * cand * DV_ * 4;           // po
    if (ws_size >= need) { ns = cand; break; }
  }
  int span = K_ / ns;
  float* pml = (float*)dyn;
  float* po = pml + (size_t)B_ * Q_ * ns * 2;

  prep_kernel<<<dim3(1024), dim3(256), 0, stream>>>(
      queries, keys, values, Wq, Wk, eq, ek, vb);
  attn_kernel<<<dim3(B_ * (Q_ / 8), ns), dim3(256), 0, stream>>>(
      eq, ek, (const unsigned*)vb, wv, vl, pml, po, ns, span);
  combine_kernel<<<dim3(B_ * Q_ / 4), dim3(256), 0, stream>>>(pml, po, out, ns);
}

// Round 7
// 47.277 us; speedup vs baseline: 1.4395x; 1.2613x over previous
//
#include <hip/hip_runtime.h>
#include <hip/hip_fp16.h>
#include <math.h>

#define B_ 4
#define Q_ 1024
#define K_ 1024
#define DIN_ 256
#define H_ 64
#define DV_ 128
#define KT 64
#define MASKV -1000000.0f
#define C2LOG2E 2.8853900817779268f   // 2*log2(e): exp(2x)=exp2(C*x)
#define LOG2E 1.4426950408889634f

__device__ __forceinline__ float fexp2(float x) {
#if __has_builtin(__builtin_amdgcn_exp2f)
  return __builtin_amdgcn_exp2f(x);
#else
  return exp2f(x);
#endif
}
__device__ __forceinline__ float frcp(float x) {
#if __has_builtin(__builtin_amdgcn_rcpf)
  return __builtin_amdgcn_rcpf(x);
#else
  return 1.0f / x;
#endif
}

// blocks [0,512): row projections EQ/EK = exp2(C * row.W), 16 rows/block
// blocks [512,1024): values -> fp16 (packed pairs; decode is free via fma_mix)
__global__ __launch_bounds__(256, 4) void prep_kernel(
    const float* __restrict__ queries, const float* __restrict__ keys,
    const float* __restrict__ values,
    const float* __restrict__ Wq, const float* __restrict__ Wk,
    float* __restrict__ eq, float* __restrict__ ek,
    unsigned short* __restrict__ vh) {
  int bid = blockIdx.x;
  int t = threadIdx.x;
  if (bid >= 512) {
    int i = ((bid - 512) * 256 + t) * 4;     // 512*256*4 = 524288 = B*K*DV
    float4 v = *(const float4*)&values[i];
    ushort4 o;
    o.x = __half_as_ushort(__float2half(v.x));
    o.y = __half_as_ushort(__float2half(v.y));
    o.z = __half_as_ushort(__float2half(v.z));
    o.w = __half_as_ushort(__float2half(v.w));
    *(ushort4*)&vh[i] = o;
    return;
  }
  int w = t >> 6, lane = t & 63;
  int r0 = __builtin_amdgcn_readfirstlane(bid * 16 + w * 4);  // rows r0..r0+3
  const float* src;
  const float* W;
  float* dst;
  if (r0 < B_ * Q_) {
    src = queries + r0 * DIN_; W = Wq; dst = eq + r0 * H_;
  } else {
    int kr = r0 - B_ * Q_;
    src = keys + kr * DIN_; W = Wk; dst = ek + kr * H_;
  }
  float a00 = 0.f, a01 = 0.f, a10 = 0.f, a11 = 0.f;
  float a20 = 0.f, a21 = 0.f, a30 = 0.f, a31 = 0.f;
#pragma unroll 8
  for (int d = 0; d < DIN_; d += 2) {
    float w0 = W[d * H_ + lane];
    float w1 = W[(d + 1) * H_ + lane];
    a00 = fmaf(w0, src[d], a00);             a01 = fmaf(w1, src[d + 1], a01);
    a10 = fmaf(w0, src[DIN_ + d], a10);      a11 = fmaf(w1, src[DIN_ + d + 1], a11);
    a20 = fmaf(w0, src[2 * DIN_ + d], a20);  a21 = fmaf(w1, src[2 * DIN_ + d + 1], a21);
    a30 = fmaf(w0, src[3 * DIN_ + d], a30);  a31 = fmaf(w1, src[3 * DIN_ + d + 1], a31);
  }
  dst[lane]          = fexp2((a00 + a01) * C2LOG2E);
  dst[H_ + lane]     = fexp2((a10 + a11) * C2LOG2E);
  dst[2 * H_ + lane] = fexp2((a20 + a21) * C2LOG2E);
  dst[3 * H_ + lane] = fexp2((a30 + a31) * C2LOG2E);
}

// Flash attention over ONE K-split span (span = 128 keys = 2 tiles at ns=8).
// ek AND V tiles staged per block into LDS (coalesced, shared by 4 waves).
// Wave owns 2 queries; lane owns 1 key slot. launch_bounds(256,4): 128 VGPRs
// so the compiler can pipeline loads (R6's (256,8) gave VGPR=32, no ILP).
__global__ __launch_bounds__(256, 4) void attn_kernel(
    const float* __restrict__ eq, const float* __restrict__ ek,
    const unsigned* __restrict__ vh32, const float* __restrict__ wv,
    const int* __restrict__ vlen,
    float* __restrict__ pml, float* __restrict__ po,
    int ns, int span) {
  __shared__ __align__(16) float ek_s[KT][H_ + 4];     // pad 4: 16B-aligned rows
  __shared__ __align__(16) unsigned v_s[KT][DV_ / 2];  // fp16 pairs
  __shared__ __align__(16) float p_s[4][2][KT];
  int t = threadIdx.x;
  int lane = t & 63;
  int w = t >> 6;
  int bid = blockIdx.x;
  int s = blockIdx.y;
  int b = bid >> 7;                           // 128 blocks per batch
  int q0 = __builtin_amdgcn_readfirstlane(((bid & 127) * 4 + w) * 2);
  int kv = vlen[b];
  int g = b * Q_ + q0;                        // global query row (and g+1)
  int k_lo = s * span;

  if (k_lo >= kv) {                           // inactive split: ml only
    if (lane == 0) {
      *(float2*)&pml[(g * ns + s) * 2] = make_float2(-1e38f, 0.f);
      *(float2*)&pml[((g + 1) * ns + s) * 2] = make_float2(-1e38f, 0.f);
    }
    return;
  }

  const float* eqa = eq + (long)g * H_;
  const float* eqb = eqa + H_;
  const float* ekb = ek + b * K_ * H_;

  // wsum = sum of w_v via wave shuffle reduce (lane-parallel)
  float wsum = wv[lane];
#pragma unroll
  for (int sh = 32; sh >= 1; sh >>= 1) wsum += __shfl_xor(wsum, sh);

  float ma = -1e38f, mb = -1e38f, la = 0.f, lb = 0.f;
  float oa0 = 0.f, oa1 = 0.f, ob0 = 0.f, ob1 = 0.f;
  int tile0 = k_lo >> 6;
  int tileE = min((kv + KT - 1) >> 6, (k_lo + span) >> 6);

  for (int tile = tile0; tile < tileE; ++tile) {
    int k0 = tile * KT;

    // ---- stage ek [64][64] f32 and V [64][64] fp16-pairs, coalesced ----
    __syncthreads();                           // prior tile's readers done
    {
      const float4* gek = (const float4*)(ekb + (size_t)k0 * H_);
      const float4* gv = (const float4*)(vh32 + (size_t)(b * K_ + k0) * (DV_ / 2));
#pragma unroll
      for (int i = 0; i < 4; ++i) {
        int f4 = i * 256 + t;
        *(float4*)&ek_s[f4 >> 4][(f4 & 15) * 4] = gek[f4];
      }
#pragma unroll
      for (int i = 0; i < 4; ++i) {
        int f4 = i * 256 + t;
        *(float4*)&v_s[f4 >> 4][(f4 & 15) * 4] = gv[f4];
      }
    }
    __syncthreads();

    // scores: x = wsum - 2 * sum_h wv[h] / (1 + EQ[h]*EK[h])
    const float* ekrow = ek_s[lane];
    float aa0 = 0.f, aa1 = 0.f, ab0 = 0.f, ab1 = 0.f;
#pragma unroll
    for (int h4 = 0; h4 < H_ / 4; ++h4) {
      float4 e4 = *(const float4*)&ekrow[h4 * 4];
#pragma unroll
      for (int j = 0; j < 4; ++j) {
        int h = h4 * 4 + j;
        float ekv = (j == 0) ? e4.x : (j == 1) ? e4.y : (j == 2) ? e4.z : e4.w;
        float wvh = wv[h];
        float ra = frcp(fmaf(ekv, eqa[h], 1.0f));
        float rb = frcp(fmaf(ekv, eqb[h], 1.0f));
        if (j & 1) { aa1 = fmaf(wvh, ra, aa1); ab1 = fmaf(wvh, rb, ab1); }
        else       { aa0 = fmaf(wvh, ra, aa0); ab0 = fmaf(wvh, rb, ab0); }
      }
    }
    float xa = fmaf(-2.f, aa0 + aa1, wsum);
    float xb = fmaf(-2.f, ab0 + ab1, wsum);
    if (k0 + lane >= kv) { xa = MASKV; xb = MASKV; }

    // wave-local online softmax for both queries (interleaved reduces)
    float mta = xa, mtb = xb;
#pragma unroll
    for (int sh = 32; sh >= 1; sh >>= 1) {
      mta = fmaxf(mta, __shfl_xor(mta, sh));
      mtb = fmaxf(mtb, __shfl_xor(mtb, sh));
    }
    float mna = fmaxf(ma, mta), mnb = fmaxf(mb, mtb);
    float pa = fexp2((xa - mna) * LOG2E);
    float pb = fexp2((xb - mnb) * LOG2E);
    float psa = pa, psb = pb;
#pragma unroll
    for (int sh = 32; sh >= 1; sh >>= 1) {
      psa += __shfl_xor(psa, sh);
      psb += __shfl_xor(psb, sh);
    }
    float sca = fexp2((ma - mna) * LOG2E);
    float scb = fexp2((mb - mnb) * LOG2E);
    la = fmaf(la, sca, psa); lb = fmaf(lb, scb, psb);
    ma = mna; mb = mnb;
    oa0 *= sca; oa1 *= sca; ob0 *= scb; ob1 *= scb;
    p_s[w][0][lane] = pa;
    p_s[w][1][lane] = pb;   // same-wave write->read; compiler inserts lgkmcnt

    // PV: p broadcast from wave-private LDS, V fp16 pairs from shared LDS
#pragma unroll 4
    for (int k4 = 0; k4 < KT / 4; ++k4) {
      float4 pa4 = *(const float4*)&p_s[w][0][k4 * 4];
      float4 pb4 = *(const float4*)&p_s[w][1][k4 * 4];
      unsigned u0 = v_s[k4 * 4 + 0][lane];
      unsigned u1 = v_s[k4 * 4 + 1][lane];
      unsigned u2 = v_s[k4 * 4 + 2][lane];
      unsigned u3 = v_s[k4 * 4 + 3][lane];
      __half2 h0 = *(__half2*)&u0, h1 = *(__half2*)&u1;
      __half2 h2 = *(__half2*)&u2, h3 = *(__half2*)&u3;
      float v00 = __low2float(h0), v01 = __high2float(h0);
      float v10 = __low2float(h1), v11 = __high2float(h1);
      float v20 = __low2float(h2), v21 = __high2float(h2);
      float v30 = __low2float(h3), v31 = __high2float(h3);
      oa0 = fmaf(pa4.x, v00, oa0); oa1 = fmaf(pa4.x, v01, oa1);
      ob0 = fmaf(pb4.x, v00, ob0); ob1 = fmaf(pb4.x, v01, ob1);
      oa0 = fmaf(pa4.y, v10, oa0); oa1 = fmaf(pa4.y, v11, oa1);
      ob0 = fmaf(pb4.y, v10, ob0); ob1 = fmaf(pb4.y, v11, ob1);
      oa0 = fmaf(pa4.z, v20, oa0); oa1 = fmaf(pa4.z, v21, oa1);
      ob0 = fmaf(pb4.z, v20, ob0); ob1 = fmaf(pb4.z, v21, ob1);
      oa0 = fmaf(pa4.w, v30, oa0); oa1 = fmaf(pa4.w, v31, oa1);
      ob0 = fmaf(pb4.w, v30, ob0); ob1 = fmaf(pb4.w, v31, ob1);
    }
  }

  // unnormalized partials
  long pbase = ((long)g * ns + s) * DV_ + lane * 2;
  *(float2*)&po[pbase] = make_float2(oa0, oa1);
  *(float2*)&po[pbase + (long)ns * DV_] = make_float2(ob0, ob1);
  if (lane == 0) {
    *(float2*)&pml[(g * ns + s) * 2] = make_float2(ma, la);
    *(float2*)&pml[((g + 1) * ns + s) * 2] = make_float2(mb, lb);
  }
}

// Merge ns partials per query row: O = sum_s o_s*e^{m_s-M}, L likewise.
__global__ __launch_bounds__(256, 4) void combine_kernel(
    const float* __restrict__ pml, const float* __restrict__ po,
    float* __restrict__ out, int ns) {
  int t = threadIdx.x;
  int lane = t & 63;
  int w = t >> 6;
  int qrow = blockIdx.x * 4 + w;
  float M = -1e38f;
  for (int s = 0; s < ns; ++s) {
    float2 v = *(const float2*)&pml[(qrow * ns + s) * 2];
    M = fmaxf(M, v.x);
  }
  float L = 0.f, ax = 0.f, ay = 0.f;
  for (int s = 0; s < ns; ++s) {
    float2 v = *(const float2*)&pml[(qrow * ns + s) * 2];
    if (v.y > 0.f) {                  // wave-uniform branch
      float wgt = fexp2((v.x - M) * LOG2E);
      L = fmaf(v.y, wgt, L);
      float2 o2 = *(const float2*)&po[((long)qrow * ns + s) * DV_ + lane * 2];
      ax = fmaf(o2.x, wgt, ax);
      ay = fmaf(o2.y, wgt, ay);
    }
  }
  float inv = frcp(L);
  *(float2*)&out[(long)qrow * DV_ + lane * 2] = make_float2(ax * inv, ay * inv);
}

extern "C" void kernel_launch(void* const* d_in, const int* in_sizes, int n_in,
                              void* d_out, int out_size, void* d_ws, size_t ws_size,
                              hipStream_t stream) {
  const float* queries = (const float*)d_in[0];
  const float* keys    = (const float*)d_in[1];
  const float* values  = (const float*)d_in[2];
  const int*   vl      = (const int*)d_in[3];
  const float* Wq      = (const float*)d_in[4];
  const float* Wk      = (const float*)d_in[5];
  const float* wv      = (const float*)d_in[6];
  float* out = (float*)d_out;

  // fixed buffers: eq 1MB, ek 1MB, vh 1MB
  float* eq = (float*)d_ws;
  float* ek = eq + (size_t)B_ * Q_ * H_;
  unsigned short* vh = (unsigned short*)(ek + (size_t)B_ * K_ * H_);
  char* dyn = (char*)(vh + (size_t)B_ * K_ * DV_);
  size_t fixed = (size_t)(dyn - (char*)d_ws);

  // choose K-split count by available workspace (deterministic per session)
  int ns = 2;
  for (int cand = 8; cand >= 2; cand >>= 1) {
    size_t need = fixed + (size_t)B_ * Q_ * cand * 8          // pml
                + (size_t)B_ * Q_ * cand * DV_ * 4;           // po
    if (ws_size >= need) { ns = cand; break; }
  }
  int span = K_ / ns;
  float* pml = (float*)dyn;
  float* po = pml + (size_t)B_ * Q_ * ns * 2;

  prep_kernel<<<dim3(1024), dim3(256), 0, stream>>>(
      queries, keys, values, Wq, Wk, eq, ek, vh);
  attn_kernel<<<dim3(B_ * (Q_ / 8), ns), dim3(256), 0, stream>>>(
      eq, ek, (const unsigned*)vh, wv, vl, pml, po, ns, span);
  combine_kernel<<<dim3(B_ * Q_ / 4), dim3(256), 0, stream>>>(pml, po, out, ns);
}